// Round 4
// baseline (27312.415 us; speedup 1.0000x reference)
//
#include <hip/hip_runtime.h>
#include <cstdint>
#include <cstddef>

#define NBLK 256
#define NTHR 512
#define B_ 64
#define P_ 196
#define E_ 512
#define A_ 512
#define D_ 512
#define M_ 512
#define V_ 1000
#define L_ 257
#define T_ 256

#define OUT_PRED  0
#define OUT_CAPS  (B_*T_*V_)                 /* 16,384,000 */
#define OUT_ALPHA (OUT_CAPS + B_*L_)         /* 16,400,448 */
#define OUT_SORT  (OUT_ALPHA + B_*T_*P_)     /* 19,611,712 */

typedef _Float16 h2 __attribute__((ext_vector_type(2)));

struct KP {
  const float* enc; const int* caps; const int* clen;
  const float* emb;
  const float* eaw; const float* eab;
  const float* daw; const float* dab;
  const float* faw; const float* fab;
  const float* wih; const float* bih;
  const float* whh; const float* bhh;
  const float* ihw; const float* ihb;
  const float* icw; const float* icb;
  const float* fbw; const float* fbb;
  const float* fcw; const float* fcb;
  float* out;
  int* bar; int* sy;
  int* sort_ind; int* dec_len;
  float* mnT; float* hG; float* hnG; float* eG; float* xG; float* att1;
  unsigned* wt2; unsigned* dft2; unsigned* fct2;
};

__device__ __forceinline__ float sigf(float x){ return 1.f/(1.f+__expf(-x)); }
__device__ __forceinline__ float tanhf_(float x){
  float ax = fabsf(x);
  float e = __expf(-2.f*ax);
  float r = (1.f-e)/(1.f+e);
  return x < 0.f ? -r : r;
}
__device__ __forceinline__ unsigned short f2bf(float x){
  unsigned u = __float_as_uint(x);
  unsigned r = (u + 0x7fffu + ((u >> 16) & 1u)) >> 16;   // RNE
  return (unsigned short)r;
}
__device__ __forceinline__ float fdot2f(h2 a, h2 b, float c){
#if __has_builtin(__builtin_amdgcn_fdot2)
  return __builtin_amdgcn_fdot2(a, b, c, false);
#else
  return c + (float)a.x*(float)b.x + (float)a.y*(float)b.y;
#endif
}
__device__ __forceinline__ unsigned packh2(float a, float b){
  h2 v; v.x = (_Float16)a; v.y = (_Float16)b;
  return __builtin_bit_cast(unsigned, v);
}
__device__ __forceinline__ h2 ash2(unsigned u){ return __builtin_bit_cast(h2, u); }

#define LD_A(p)     __hip_atomic_load((p), __ATOMIC_RELAXED, __HIP_MEMORY_SCOPE_AGENT)
#define ST_A(p,v)   __hip_atomic_store((p),(v), __ATOMIC_RELAXED, __HIP_MEMORY_SCOPE_AGENT)
#define ST_REL(p,v) __hip_atomic_store((p),(v), __ATOMIC_RELEASE, __HIP_MEMORY_SCOPE_AGENT)
#define FAA(p)      __hip_atomic_fetch_add((p),1, __ATOMIC_RELAXED, __HIP_MEMORY_SCOPE_AGENT)
// coherent (LLC, cache-bypassing) data path -- no cache-flushing fences needed
__device__ __forceinline__ float ldg_c(const float* p){
  return __hip_atomic_load(p, __ATOMIC_RELAXED, __HIP_MEMORY_SCOPE_AGENT);
}
__device__ __forceinline__ void stg_c(float* p, float v){
  __hip_atomic_store(p, v, __ATOMIC_RELAXED, __HIP_MEMORY_SCOPE_AGENT);
}

// Pre-phase-only grid barrier (full fences; heavyweight, used 3x total).
__device__ __forceinline__ void gridbar(int* bar, int blk){
  __syncthreads();
  if (threadIdx.x == 0){
    __builtin_amdgcn_fence(__ATOMIC_RELEASE, "agent");
    int s = LD_A(&bar[144]);
    int* leaf = &bar[(blk & 7)*16];
    if (FAA(leaf) == 31){
      ST_A(leaf, 0);
      if (FAA(&bar[128]) == 7){
        ST_A(&bar[128], 0);
        ST_REL(&bar[144], s+1);
      }
    }
    while (LD_A(&bar[144]) == s) __builtin_amdgcn_s_sleep(2);
    __builtin_amdgcn_fence(__ATOMIC_ACQUIRE, "agent");
  }
  __syncthreads();
}

// Lightweight 4-block group sync: monotonic counter, no cache flushes.
// __syncthreads before the FAA drains every wave's vmem (compiler emits
// s_waitcnt vmcnt(0) before s_barrier), so all sc1 data stores are at LLC
// before the counter bump. Consumers' sc1 loads bypass stale caches.
__device__ __forceinline__ void gsync(int* ctr, int target){
  __syncthreads();
  if (threadIdx.x == 0){
    FAA(ctr);
    while (LD_A(ctr) < target) __builtin_amdgcn_s_sleep(1);
    asm volatile("" ::: "memory");
  }
  __syncthreads();
}

// LDS map (134,784 B):
//   [0,      50176) att1L   bf16[49][512]     resident
//   [50176, 105472) encT2   h2 [512][27]      resident (p-pair packed, padded)
//   [105472,111616) xf      f32[1536]
//   [111616,114688) xL2     h2 [768]
//   [114688,116736) hL      f32[512]
//   [116736,117760) hL2     h2 [256]
//   [117760,119808) a2L     f32[512]
//   [119808,121856) gateL   f32[512]
//   [121856,123904) fwL     f32[512]
//   [123904,124928) eL      f32[256]
//   [124928,125952) alphaL  f32[256]
//   [125952,126080) alpha2L h2 [32]
//   [126080,126592) cL      f32[128]          persistent LSTM cell state
//   [126592,134784) red     f32[2048]
// Pre1 tile GEMM aliases [0, 76032) -- dead before residents are written.
__global__ __launch_bounds__(NTHR, 2) void dec_kernel(KP p){
  __shared__ __align__(16) char smem_raw[134784];
  unsigned short* att1L = (unsigned short*)smem_raw;
  unsigned* encT2  = (unsigned*)(smem_raw + 50176);
  float* xf        = (float*)(smem_raw + 105472);
  unsigned* xL2    = (unsigned*)(smem_raw + 111616);
  float* hL        = (float*)(smem_raw + 114688);
  unsigned* hL2    = (unsigned*)(smem_raw + 116736);
  float* a2L       = (float*)(smem_raw + 117760);
  float* gateL     = (float*)(smem_raw + 119808);
  float* fwL       = (float*)(smem_raw + 121856);
  float* eL        = (float*)(smem_raw + 123904);
  float* alphaL    = (float*)(smem_raw + 124928);
  unsigned* alpha2L= (unsigned*)(smem_raw + 125952);
  float* cL        = (float*)(smem_raw + 126080);
  float* red       = (float*)(smem_raw + 126592);

  const int blk  = blockIdx.x;
  const int tid  = threadIdx.x;
  const int lane = tid & 63;
  const int wave = tid >> 6;
  const int b    = blk >> 2;          // batch row owned by this group
  const int q    = blk & 3;           // quadrant within group
  int* syc = &p.sy[b*16];             // [0]=s1(e) [1]=s2(x) [2]=s3(h)

  // ---------------- Pre0: stable descending argsort + caps gather ----------------
  if (blk == 0){
    if (tid < B_){
      int lb = p.clen[tid];
      int rank = 0;
      for (int j = 0; j < B_; j++){
        int lj = p.clen[j];
        rank += (lj > lb) || (lj == lb && j < tid);
      }
      p.sort_ind[rank] = tid;
      p.dec_len[rank]  = lb - 1;
      p.out[OUT_SORT + rank] = (float)tid;
    }
    __syncthreads();
    for (int idx = tid; idx < B_*L_; idx += NTHR){
      int bb = idx / L_;
      int l = idx - bb*L_;
      int sbv = p.sort_ind[bb];
      p.out[OUT_CAPS + idx] = (float)p.caps[sbv*L_ + l];
    }
  }
  gridbar(p.bar, blk);

  const int sb  = p.sort_ind[b];
  const int dlb = p.dec_len[b];

  // ---------------- Pre1: att1 = enc_s @ enc_att_w^T + b (196 tiles) + mean (64) ----------------
  for (int task = blk; task < 260; task += NBLK){
    if (task < 196){
      const int r0 = task*64;
      float* wL = (float*)smem_raw;             // [512][33]
      float* eLt = (float*)smem_raw + 512*33;   // [64][33]
      const int tx = tid & 31, ty = tid >> 5;   // ty<16
      float acc[4][16];
      #pragma unroll
      for (int i=0;i<4;i++)
        #pragma unroll
        for (int j=0;j<16;j++) acc[i][j] = 0.f;
      for (int k0 = 0; k0 < 512; k0 += 32){
        __syncthreads();
        for (int i = tid; i < 512*32; i += NTHR){
          int a = i >> 5, kk = i & 31;
          wL[a*33 + kk] = p.eaw[a*512 + k0 + kk];
        }
        for (int i = tid; i < 64*32; i += NTHR){
          int rl = i >> 5, kk = i & 31;
          int r = r0 + rl;
          int bb = r / 196;
          int pp = r - bb*196;
          int sbv = p.sort_ind[bb];
          eLt[rl*33 + kk] = p.enc[((size_t)sbv*196 + pp)*512 + k0 + kk];
        }
        __syncthreads();
        for (int kk = 0; kk < 32; kk++){
          float ev[4];
          #pragma unroll
          for (int ii=0;ii<4;ii++) ev[ii] = eLt[(ty*4+ii)*33 + kk];
          #pragma unroll
          for (int jj=0;jj<16;jj++){
            float wv = wL[(tx + 32*jj)*33 + kk];
            #pragma unroll
            for (int ii=0;ii<4;ii++) acc[ii][jj] = fmaf(ev[ii], wv, acc[ii][jj]);
          }
        }
      }
      #pragma unroll
      for (int jj=0;jj<16;jj++){
        int a = tx + 32*jj;
        float bbv = p.eab[a];
        #pragma unroll
        for (int ii=0;ii<4;ii++){
          int r = r0 + ty*4 + ii;
          p.att1[(size_t)r*512 + a] = acc[ii][jj] + bbv;
        }
      }
      __syncthreads();
    } else {
      int bb = task - 196;
      int sbv = p.sort_ind[bb];
      const float* eb = p.enc + (size_t)sbv*P_*E_;
      for (int e = tid; e < E_; e += NTHR){
        float s = 0.f;
        for (int pp = 0; pp < P_; pp++) s += eb[pp*E_ + e];
        p.mnT[bb*512 + e] = s * (1.f/196.f);
      }
    }
  }
  gridbar(p.bar, blk);

  // ---------------- Pre1.5: resident LDS + weight transposes + h0/c0 ----------------
  // (a) att1 -> bf16 LDS; enc -> p-pair-packed f16 LDS; full_att_w
  for (int idx = tid; idx < 49*512; idx += NTHR){
    int pp = idx >> 9, a = idx & 511;
    att1L[idx] = f2bf(p.att1[((size_t)(b*196 + q*49 + pp))*512 + a]);
  }
  for (int i = tid; i < 512*25; i += NTHR){
    int p2 = i >> 9, e = i & 511;
    int pr0 = q*49 + 2*p2;
    float e0 = p.enc[((size_t)sb*196 + pr0)*512 + e];
    float e1 = (2*p2+1 < 49) ? p.enc[((size_t)sb*196 + pr0 + 1)*512 + e] : 0.f;
    encT2[e*27 + p2] = packh2(e0, e1);
  }
  fwL[tid] = p.faw[tid];
  // (b) f16 pair-packed transposed weights
  for (int kk = 0; kk < 3; kk++){
    int k2 = blk*3 + kk, k = 2*k2;
    for (int c = tid; c < 2048; c += NTHR){
      int j = c >> 2, g = c & 3;
      float w0, w1;
      if (k < 1024){ const float* r = p.wih + (size_t)(g*512+j)*1024 + k; w0 = r[0]; w1 = r[1]; }
      else         { const float* r = p.whh + (size_t)(g*512+j)*512 + (k-1024); w0 = r[0]; w1 = r[1]; }
      p.wt2[(size_t)k2*2048 + c] = packh2(w0, w1);
    }
  }
  {
    int k2 = blk, k = 2*k2;
    for (int i = tid; i < 1024; i += NTHR){
      int c = i >> 1, d = i & 1;
      const float* r = (d ? p.fbw : p.daw) + (size_t)c*512 + k;
      p.dft2[k2*1024 + i] = packh2(r[0], r[1]);
    }
    for (int v = tid; v < 1024; v += NTHR){
      unsigned u = 0;
      if (v < 1000){ const float* r = p.fcw + (size_t)v*512 + k; u = packh2(r[0], r[1]); }
      p.fct2[k2*1024 + v] = u;
    }
  }
  // (c) h0/c0 for own (b, j-range)
  hL[tid] = p.mnT[b*512 + tid];
  __syncthreads();
  {
    int r = tid & 255, kh = tid >> 8;
    int which = r >> 7, jj = r & 127;
    const float* row = (which ? p.icw : p.ihw) + (size_t)(q*128+jj)*512;
    float acc = 0.f;
    for (int k = kh*256; k < kh*256+256; k++) acc += row[k]*hL[k];
    red[kh*256 + r] = acc;
  }
  __syncthreads();
  if (tid < 256){
    int which = tid >> 7, jj = tid & 127;
    float v = red[tid] + red[256+tid] + (which ? p.icb : p.ihb)[q*128+jj];
    if (which == 0) stg_c(&p.hG[b*512 + q*128 + jj], v);
    else cL[jj] = v;
  }
  gridbar(p.bar, blk);

  const float fab0 = p.fab[0];

  // ---------------- time loop: zero grid barriers, 3 group syncs/step ----------------
  for (int t = 0; t < T_; t++){
    // wait h(t) complete (s3 from step t-1)
    if (tid == 0){
      while (LD_A(&syc[2]) < 4*t) __builtin_amdgcn_s_sleep(1);
      asm volatile("" ::: "memory");
    }
    __syncthreads();

    // stage h(t); stage packed h_new(t-1) for preds; zero own awe quarter
    hL[tid] = ldg_c(&p.hG[b*512 + tid]);
    if (t > 0 && tid < 256)
      xL2[tid] = packh2(ldg_c(&p.hnG[b*512 + 2*tid]), ldg_c(&p.hnG[b*512 + 2*tid + 1]));
    if (t > 0 && tid < 128) stg_c(&p.xG[b*512 + q*128 + tid], 0.f);
    __syncthreads();

    if (tid < 256) hL2[tid] = packh2(hL[2*tid], hL[2*tid+1]);

    // preds(t-1): 250 cols per block, 2-way k-split
    if (t > 0){
      int vv = tid & 255, kh = tid >> 8, v = q*250 + vv;
      float acc = 0.f;
      for (int k20 = kh*128; k20 < kh*128 + 128; k20 += 4){
        uint4 hq = *(const uint4*)(xL2 + k20);
        acc = fdot2f(ash2(p.fct2[(k20+0)*1024 + v]), ash2(hq.x), acc);
        acc = fdot2f(ash2(p.fct2[(k20+1)*1024 + v]), ash2(hq.y), acc);
        acc = fdot2f(ash2(p.fct2[(k20+2)*1024 + v]), ash2(hq.z), acc);
        acc = fdot2f(ash2(p.fct2[(k20+3)*1024 + v]), ash2(hq.w), acc);
      }
      red[kh*256 + vv] = acc;
    }
    __syncthreads();
    if (t > 0 && tid < 250){
      int v = q*250 + tid;
      float sum = red[tid] + red[256+tid] + p.fcb[v];
      bool mm = (t-1) < dlb;
      p.out[OUT_PRED + ((size_t)b*T_ + (t-1))*V_ + v] = mm ? sum : 0.f;
    }

    // a2 + gate: full 512 cols each, locally (4x group-redundant, zero sync)
    {
      float aa = p.dab[tid], ag = p.fbb[tid];
      const uint2* df = (const uint2*)p.dft2;
      for (int k20 = 0; k20 < 256; k20 += 4){
        uint4 hq = *(const uint4*)(hL2 + k20);
        uint2 w0 = df[(k20+0)*512 + tid];
        uint2 w1 = df[(k20+1)*512 + tid];
        uint2 w2 = df[(k20+2)*512 + tid];
        uint2 w3 = df[(k20+3)*512 + tid];
        aa = fdot2f(ash2(w0.x), ash2(hq.x), aa); ag = fdot2f(ash2(w0.y), ash2(hq.x), ag);
        aa = fdot2f(ash2(w1.x), ash2(hq.y), aa); ag = fdot2f(ash2(w1.y), ash2(hq.y), ag);
        aa = fdot2f(ash2(w2.x), ash2(hq.z), aa); ag = fdot2f(ash2(w2.y), ash2(hq.z), ag);
        aa = fdot2f(ash2(w3.x), ash2(hq.w), aa); ag = fdot2f(ash2(w3.y), ash2(hq.w), ag);
      }
      a2L[tid] = aa;
      gateL[tid] = sigf(ag);
    }
    __syncthreads();

    // e for own 49 rows from LDS bf16 att1
    {
      float4 aA = ((float4*)a2L)[lane*2], aB = ((float4*)a2L)[lane*2+1];
      float4 fA = ((float4*)fwL)[lane*2], fB = ((float4*)fwL)[lane*2+1];
      for (int pp = wave; pp < 49; pp += 8){
        uint4 raw = ((const uint4*)att1L)[pp*64 + lane];
        float s =
          fmaxf(__uint_as_float(raw.x << 16)        + aA.x, 0.f)*fA.x +
          fmaxf(__uint_as_float(raw.x & 0xffff0000u)+ aA.y, 0.f)*fA.y +
          fmaxf(__uint_as_float(raw.y << 16)        + aA.z, 0.f)*fA.z +
          fmaxf(__uint_as_float(raw.y & 0xffff0000u)+ aA.w, 0.f)*fA.w +
          fmaxf(__uint_as_float(raw.z << 16)        + aB.x, 0.f)*fB.x +
          fmaxf(__uint_as_float(raw.z & 0xffff0000u)+ aB.y, 0.f)*fB.y +
          fmaxf(__uint_as_float(raw.w << 16)        + aB.z, 0.f)*fB.z +
          fmaxf(__uint_as_float(raw.w & 0xffff0000u)+ aB.w, 0.f)*fB.w;
        #pragma unroll
        for (int o = 32; o > 0; o >>= 1) s += __shfl_down(s, o);
        if (lane == 0) stg_c(&p.eG[b*256 + q*49 + pp], s + fab0);
      }
    }
    gsync(&syc[0], 4*(t+1));           // S1: e complete

    if (tid < 196) eL[tid] = ldg_c(&p.eG[b*256 + tid]);
    __syncthreads();
    if (wave == 0){
      float mx = -1e30f;
      for (int i = lane; i < P_; i += 64) mx = fmaxf(mx, eL[i]);
      #pragma unroll
      for (int o = 32; o > 0; o >>= 1) mx = fmaxf(mx, __shfl_xor(mx, o));
      float sum = 0.f;
      for (int i = lane; i < P_; i += 64){
        float ex = __expf(eL[i] - mx);
        alphaL[i] = ex;
        sum += ex;
      }
      #pragma unroll
      for (int o = 32; o > 0; o >>= 1) sum += __shfl_xor(sum, o);
      float inv = 1.f / sum;
      for (int i = lane; i < P_; i += 64) alphaL[i] *= inv;
    }
    __syncthreads();
    {
      bool mb = t < dlb;
      if (tid < 49)
        p.out[OUT_ALPHA + ((size_t)b*T_ + t)*P_ + q*49 + tid] = mb ? alphaL[q*49 + tid] : 0.f;
      if (tid < 25){
        float a0 = alphaL[q*49 + 2*tid];
        float a1 = (2*tid+1 < 49) ? alphaL[q*49 + 2*tid + 1] : 0.f;
        alpha2L[tid] = packh2(a0, a1);
      }
    }
    __syncthreads();

    // awe partial (own 49 rows, all 512 e) * gate -> atomicAdd
    {
      const unsigned* ec = encT2 + tid*27;
      float s = 0.f;
      #pragma unroll 5
      for (int p2 = 0; p2 < 25; p2++)
        s = fdot2f(ash2(ec[p2]), ash2(alpha2L[p2]), s);
      __hip_atomic_fetch_add(&p.xG[b*512 + tid], gateL[tid]*s,
                             __ATOMIC_RELAXED, __HIP_MEMORY_SCOPE_AGENT);
    }
    gsync(&syc[1], 4*(t+1));           // S2: x complete

    // stage + pack x = [emb | gate*awe | h]
    {
      int cap = p.caps[sb*L_ + t];
      xf[tid]        = p.emb[(size_t)cap*M_ + tid];
      xf[512 + tid]  = ldg_c(&p.xG[b*512 + tid]);
      xf[1024 + tid] = hL[tid];
    }
    __syncthreads();
    xL2[tid] = packh2(xf[2*tid], xf[2*tid+1]);
    if (tid < 256) xL2[512 + tid] = hL2[tid];
    __syncthreads();

    // gates GEMM: 512 cols (j-range q*128, c=j*4+g), col-pair x 2-way k-split
    {
      const int cc = tid & 255, kh = tid >> 8;
      const uint2* wt = (const uint2*)p.wt2;
      const int cbase = q*256 + cc;
      float a0 = 0.f, a1 = 0.f;
      for (int k20 = kh*384; k20 < kh*384 + 384; k20 += 4){
        uint4 xq = *(const uint4*)(xL2 + k20);
        uint2 w0 = wt[(k20+0)*1024 + cbase];
        uint2 w1 = wt[(k20+1)*1024 + cbase];
        uint2 w2 = wt[(k20+2)*1024 + cbase];
        uint2 w3 = wt[(k20+3)*1024 + cbase];
        a0 = fdot2f(ash2(w0.x), ash2(xq.x), a0); a1 = fdot2f(ash2(w0.y), ash2(xq.x), a1);
        a0 = fdot2f(ash2(w1.x), ash2(xq.y), a0); a1 = fdot2f(ash2(w1.y), ash2(xq.y), a1);
        a0 = fdot2f(ash2(w2.x), ash2(xq.z), a0); a1 = fdot2f(ash2(w2.y), ash2(xq.z), a1);
        a0 = fdot2f(ash2(w3.x), ash2(xq.w), a0); a1 = fdot2f(ash2(w3.y), ash2(xq.w), a1);
      }
      red[kh*512 + 2*cc]     = a0;
      red[kh*512 + 2*cc + 1] = a1;
    }
    __syncthreads();
    {
      int c = q*512 + tid, j = c >> 2, g = c & 3;
      red[1024 + tid] = red[tid] + red[512 + tid] + p.bih[g*512 + j] + p.bhh[g*512 + j];
    }
    __syncthreads();
    if (tid < 128){
      int jj = tid;
      float i_s = sigf(red[1024 + jj*4 + 0]);
      float f_s = sigf(red[1024 + jj*4 + 1]);
      float g_t = tanhf_(red[1024 + jj*4 + 2]);
      float o_s = sigf(red[1024 + jj*4 + 3]);
      float c_old = cL[jj];
      float c_new = f_s*c_old + i_s*g_t;
      float h_new = o_s*tanhf_(c_new);
      bool m = t < dlb;
      float h2v = m ? h_new : hL[q*128 + jj];
      float c2v = m ? c_new : c_old;
      cL[jj] = c2v;
      stg_c(&p.hnG[b*512 + q*128 + jj], h_new);
      stg_c(&p.hG [b*512 + q*128 + jj], h2v);
    }
    // S3 increment only (wait happens at next loop top)
    __syncthreads();
    if (tid == 0) FAA(&syc[2]);
  }

  // ---- final preds for t = T-1 ----
  if (tid == 0){
    while (LD_A(&syc[2]) < 4*T_) __builtin_amdgcn_s_sleep(1);
    asm volatile("" ::: "memory");
  }
  __syncthreads();
  if (tid < 256)
    xL2[tid] = packh2(ldg_c(&p.hnG[b*512 + 2*tid]), ldg_c(&p.hnG[b*512 + 2*tid + 1]));
  __syncthreads();
  {
    int vv = tid & 255, kh = tid >> 8, v = q*250 + vv;
    float acc = 0.f;
    for (int k20 = kh*128; k20 < kh*128 + 128; k20 += 4){
      uint4 hq = *(const uint4*)(xL2 + k20);
      acc = fdot2f(ash2(p.fct2[(k20+0)*1024 + v]), ash2(hq.x), acc);
      acc = fdot2f(ash2(p.fct2[(k20+1)*1024 + v]), ash2(hq.y), acc);
      acc = fdot2f(ash2(p.fct2[(k20+2)*1024 + v]), ash2(hq.z), acc);
      acc = fdot2f(ash2(p.fct2[(k20+3)*1024 + v]), ash2(hq.w), acc);
    }
    red[kh*256 + vv] = acc;
  }
  __syncthreads();
  if (tid < 250){
    int v = q*250 + tid;
    float sum = red[tid] + red[256+tid] + p.fcb[v];
    bool mm = (T_-1) < dlb;
    p.out[OUT_PRED + ((size_t)b*T_ + (T_-1))*V_ + v] = mm ? sum : 0.f;
  }
}

extern "C" void kernel_launch(void* const* d_in, const int* in_sizes, int n_in,
                              void* d_out, int out_size, void* d_ws, size_t ws_size,
                              hipStream_t stream){
  (void)in_sizes; (void)n_in; (void)out_size; (void)ws_size;
  KP p;
  p.enc  = (const float*)d_in[0];
  p.caps = (const int*)  d_in[1];
  p.clen = (const int*)  d_in[2];
  p.emb  = (const float*)d_in[3];
  p.eaw  = (const float*)d_in[4];  p.eab = (const float*)d_in[5];
  p.daw  = (const float*)d_in[6];  p.dab = (const float*)d_in[7];
  p.faw  = (const float*)d_in[8];  p.fab = (const float*)d_in[9];
  p.wih  = (const float*)d_in[10]; p.bih = (const float*)d_in[11];
  p.whh  = (const float*)d_in[12]; p.bhh = (const float*)d_in[13];
  p.ihw  = (const float*)d_in[14]; p.ihb = (const float*)d_in[15];
  p.icw  = (const float*)d_in[16]; p.icb = (const float*)d_in[17];
  p.fbw  = (const float*)d_in[18]; p.fbb = (const float*)d_in[19];
  p.fcw  = (const float*)d_in[20]; p.fcb = (const float*)d_in[21];
  p.out  = (float*)d_out;

  char* ws = (char*)d_ws;
  size_t off = 0;
  p.bar = (int*)(ws + off); off += 1024;
  p.sy  = (int*)(ws + off); off += 64*16*4;          // 4096
  p.xG  = (float*)(ws + off); off += (size_t)B_*512*4; // 131072
  size_t zero_bytes = off;                            // memset region
  p.sort_ind = (int*)(ws + off); off += 64*4;
  p.dec_len  = (int*)(ws + off); off += 64*4;
  off = (off + 255) & ~(size_t)255;
  p.mnT  = (float*)(ws + off); off += (size_t)B_*512*4;
  p.hG   = (float*)(ws + off); off += (size_t)B_*512*4;
  p.hnG  = (float*)(ws + off); off += (size_t)B_*512*4;
  p.eG   = (float*)(ws + off); off += (size_t)B_*256*4;
  p.att1 = (float*)(ws + off); off += (size_t)B_*P_*A_*4;
  p.wt2  = (unsigned*)(ws + off); off += (size_t)768*2048*4;
  p.dft2 = (unsigned*)(ws + off); off += (size_t)256*1024*4;
  p.fct2 = (unsigned*)(ws + off); off += (size_t)256*1024*4;

  hipMemsetAsync(ws, 0, zero_bytes, stream);

  void* args[] = { (void*)&p };
  hipLaunchCooperativeKernel((const void*)dec_kernel,
                             dim3(NBLK), dim3(NTHR), args, 0, stream);
}

// Round 5
// 12699.542 us; speedup vs baseline: 2.1507x; 2.1507x over previous
//
#include <hip/hip_runtime.h>
#include <cstdint>
#include <cstddef>

#define NBLK 256
#define NTHR 512
#define B_ 64
#define P_ 196
#define E_ 512
#define A_ 512
#define D_ 512
#define M_ 512
#define V_ 1000
#define L_ 257
#define T_ 256

#define OUT_PRED  0
#define OUT_CAPS  (B_*T_*V_)                 /* 16,384,000 */
#define OUT_ALPHA (OUT_CAPS + B_*L_)         /* 16,400,448 */
#define OUT_SORT  (OUT_ALPHA + B_*T_*P_)     /* 19,611,712 */

typedef _Float16 h2 __attribute__((ext_vector_type(2)));

struct KP {
  const float* enc; const int* caps; const int* clen;
  const float* emb;
  const float* eaw; const float* eab;
  const float* daw; const float* dab;
  const float* faw; const float* fab;
  const float* wih; const float* bih;
  const float* whh; const float* bhh;
  const float* ihw; const float* ihb;
  const float* icw; const float* icb;
  const float* fbw; const float* fbb;
  const float* fcw; const float* fcb;
  float* out;
  int* bar; int* tb; int* sy;
  int* sort_ind; int* dec_len;
  float* mnT; float* hA; float* hB; float* hnG;
  float* a2G; float* gateG; float* xG; float* eG; float* att1;
  unsigned* wA2; unsigned* wG2;
};

__device__ __forceinline__ float sigf(float x){ return 1.f/(1.f+__expf(-x)); }
__device__ __forceinline__ float tanhf_(float x){
  float ax = fabsf(x);
  float e = __expf(-2.f*ax);
  float r = (1.f-e)/(1.f+e);
  return x < 0.f ? -r : r;
}
__device__ __forceinline__ unsigned short f2bf(float x){
  unsigned u = __float_as_uint(x);
  unsigned r = (u + 0x7fffu + ((u >> 16) & 1u)) >> 16;   // RNE
  return (unsigned short)r;
}
__device__ __forceinline__ float fdot2f(h2 a, h2 b, float c){
#if __has_builtin(__builtin_amdgcn_fdot2)
  return __builtin_amdgcn_fdot2(a, b, c, false);
#else
  return c + (float)a.x*(float)b.x + (float)a.y*(float)b.y;
#endif
}
__device__ __forceinline__ unsigned packh2(float a, float b){
  h2 v; v.x = (_Float16)a; v.y = (_Float16)b;
  return __builtin_bit_cast(unsigned, v);
}
__device__ __forceinline__ h2 ash2(unsigned u){ return __builtin_bit_cast(h2, u); }

#define LD_A(p)     __hip_atomic_load((p), __ATOMIC_RELAXED, __HIP_MEMORY_SCOPE_AGENT)
#define ST_A(p,v)   __hip_atomic_store((p),(v), __ATOMIC_RELAXED, __HIP_MEMORY_SCOPE_AGENT)
#define ST_REL(p,v) __hip_atomic_store((p),(v), __ATOMIC_RELEASE, __HIP_MEMORY_SCOPE_AGENT)
#define FAA(p)      __hip_atomic_fetch_add((p),1, __ATOMIC_RELAXED, __HIP_MEMORY_SCOPE_AGENT)
__device__ __forceinline__ float ldg_c(const float* p){
  return __hip_atomic_load(p, __ATOMIC_RELAXED, __HIP_MEMORY_SCOPE_AGENT);
}
__device__ __forceinline__ float2 ldg2_c(const float* p){
  unsigned long long u = __hip_atomic_load((const unsigned long long*)p,
                       __ATOMIC_RELAXED, __HIP_MEMORY_SCOPE_AGENT);
  return __builtin_bit_cast(float2, u);
}
__device__ __forceinline__ void stg_c(float* p, float v){
  __hip_atomic_store(p, v, __ATOMIC_RELAXED, __HIP_MEMORY_SCOPE_AGENT);
}

// Fenced grid barrier -- pre-phase only (3 uses; flushes L2 so normal-load
// consumers of pre-phase tables see fresh data).
__device__ __forceinline__ void gridbar(int* bar, int blk){
  __syncthreads();
  if (threadIdx.x == 0){
    __builtin_amdgcn_fence(__ATOMIC_RELEASE, "agent");
    int s = LD_A(&bar[144]);
    int* leaf = &bar[(blk & 7)*16];
    if (FAA(leaf) == 31){
      ST_A(leaf, 0);
      if (FAA(&bar[128]) == 7){
        ST_A(&bar[128], 0);
        ST_REL(&bar[144], s+1);
      }
    }
    while (LD_A(&bar[144]) == s) __builtin_amdgcn_s_sleep(2);
    __builtin_amdgcn_fence(__ATOMIC_ACQUIRE, "agent");
  }
  __syncthreads();
}

// Monotonic fence-free tree barrier for the time loop. No resets -> no
// counter-clobber races. Data ordering: __syncthreads drains vmcnt before
// thread0's FAA, so all sc1 stores are IC-visible before arrival is
// published (mechanism empirically validated in R4's gsync).
__device__ __forceinline__ void treebar(int* tb, int blk, int ep){
  __syncthreads();
  if (threadIdx.x == 0){
    int* leaf = &tb[(blk & 7)*16];
    int prev = FAA(leaf);
    if (prev == ep*32 - 1){
      int pr = FAA(&tb[128]);
      if (pr == ep*8 - 1) ST_A(&tb[144], ep);
    }
    while (LD_A(&tb[144]) < ep) __builtin_amdgcn_s_sleep(2);
    asm volatile("" ::: "memory");
  }
  __syncthreads();
}

// LDS map (max ~134.7 KB):
//   [0,      50176) att1L  bf16[49][512]  resident (P2 identity: b=blk>>2,q=blk&3)
//   [50176, 105472) encT2  h2[512][27]    resident
//   [105472,107520) fwL    f32[512]       resident
//   [107520,108032) cL     f32[16][8]     persistent LSTM cell slice (P3 identity)
//   [108032,   ...) SCRATCH (phase-local, aliased):
//     P1: hL2 u32[8][256] (8 KB) / hnL2 u32[8][256] (8 KB)
//     P3: xL2 u32[8][768] (24 KB), red f32[64][8] (2 KB)
//     P2: a2L[512] gateL[512] eL[256] alphaL[256] alpha2L[32]
// Pre1 tile GEMM aliases [0, 76032) -- dead before residents are written.
__global__ __launch_bounds__(NTHR, 2) void dec_kernel(KP p){
  __shared__ __align__(16) char smem_raw[135168];
  unsigned short* att1L = (unsigned short*)smem_raw;
  unsigned* encT2  = (unsigned*)(smem_raw + 50176);
  float* fwL       = (float*)(smem_raw + 105472);
  float* cL        = (float*)(smem_raw + 107520);
  char* SCR        = smem_raw + 108032;
  unsigned* hL2    = (unsigned*)SCR;                 // P1
  unsigned* hnL2   = (unsigned*)(SCR + 8192);        // P1
  unsigned* xL2    = (unsigned*)SCR;                 // P3
  float* red       = (float*)(SCR + 24576);          // P3
  float* a2L       = (float*)SCR;                    // P2
  float* gateL     = (float*)(SCR + 2048);
  float* eL        = (float*)(SCR + 4096);
  float* alphaL    = (float*)(SCR + 5120);
  unsigned* alpha2L= (unsigned*)(SCR + 6144);

  const int blk  = blockIdx.x;
  const int tid  = threadIdx.x;
  const int lane = tid & 63;
  const int wave = tid >> 6;
  // P2 identity
  const int b    = blk >> 2;
  const int q    = blk & 3;
  // P1/P3 identity: column-tile x batch-octet
  const int ct   = blk & 31;          // 0..31
  const int bt   = blk >> 5;          // 0..7

  // ---------------- Pre0: stable descending argsort + caps gather ----------------
  if (blk == 0){
    if (tid < B_){
      int lb = p.clen[tid];
      int rank = 0;
      for (int j = 0; j < B_; j++){
        int lj = p.clen[j];
        rank += (lj > lb) || (lj == lb && j < tid);
      }
      p.sort_ind[rank] = tid;
      p.dec_len[rank]  = lb - 1;
      p.out[OUT_SORT + rank] = (float)tid;
    }
    __syncthreads();
    for (int idx = tid; idx < B_*L_; idx += NTHR){
      int bb = idx / L_;
      int l = idx - bb*L_;
      int sbv = p.sort_ind[bb];
      p.out[OUT_CAPS + idx] = (float)p.caps[sbv*L_ + l];
    }
  }
  gridbar(p.bar, blk);

  const int sb  = p.sort_ind[b];
  const int dlb = p.dec_len[b];

  // ---------------- Pre1: att1 = enc_s @ enc_att_w^T + b (196 tiles) + mean (64) ----------------
  for (int task = blk; task < 260; task += NBLK){
    if (task < 196){
      const int r0 = task*64;
      float* wL = (float*)smem_raw;             // [512][33]
      float* eLt = (float*)smem_raw + 512*33;   // [64][33]
      const int tx = tid & 31, ty = tid >> 5;   // ty<16
      float acc[4][16];
      #pragma unroll
      for (int i=0;i<4;i++)
        #pragma unroll
        for (int j=0;j<16;j++) acc[i][j] = 0.f;
      for (int k0 = 0; k0 < 512; k0 += 32){
        __syncthreads();
        for (int i = tid; i < 512*32; i += NTHR){
          int a = i >> 5, kk = i & 31;
          wL[a*33 + kk] = p.eaw[a*512 + k0 + kk];
        }
        for (int i = tid; i < 64*32; i += NTHR){
          int rl = i >> 5, kk = i & 31;
          int r = r0 + rl;
          int bb = r / 196;
          int pp = r - bb*196;
          int sbv = p.sort_ind[bb];
          eLt[rl*33 + kk] = p.enc[((size_t)sbv*196 + pp)*512 + k0 + kk];
        }
        __syncthreads();
        for (int kk = 0; kk < 32; kk++){
          float ev[4];
          #pragma unroll
          for (int ii=0;ii<4;ii++) ev[ii] = eLt[(ty*4+ii)*33 + kk];
          #pragma unroll
          for (int jj=0;jj<16;jj++){
            float wv = wL[(tx + 32*jj)*33 + kk];
            #pragma unroll
            for (int ii=0;ii<4;ii++) acc[ii][jj] = fmaf(ev[ii], wv, acc[ii][jj]);
          }
        }
      }
      #pragma unroll
      for (int jj=0;jj<16;jj++){
        int a = tx + 32*jj;
        float bbv = p.eab[a];
        #pragma unroll
        for (int ii=0;ii<4;ii++){
          int r = r0 + ty*4 + ii;
          p.att1[(size_t)r*512 + a] = acc[ii][jj] + bbv;
        }
      }
      __syncthreads();
    } else {
      int bb = task - 196;
      int sbv = p.sort_ind[bb];
      const float* eb = p.enc + (size_t)sbv*P_*E_;
      for (int e = tid; e < E_; e += NTHR){
        float s = 0.f;
        for (int pp = 0; pp < P_; pp++) s += eb[pp*E_ + e];
        p.mnT[bb*512 + e] = s * (1.f/196.f);
      }
    }
  }
  gridbar(p.bar, blk);

  // ---------------- Pre2: residents + f16 weight tables + h0/c0 ----------------
  // (a) P2 residents
  for (int idx = tid; idx < 49*512; idx += NTHR){
    int pp = idx >> 9, a = idx & 511;
    att1L[idx] = f2bf(p.att1[((size_t)(b*196 + q*49 + pp))*512 + a]);
  }
  for (int i = tid; i < 512*25; i += NTHR){
    int p2 = i >> 9, e = i & 511;
    int pr0 = q*49 + 2*p2;
    float e0 = p.enc[((size_t)sb*196 + pr0)*512 + e];
    float e1 = (2*p2+1 < 49) ? p.enc[((size_t)sb*196 + pr0 + 1)*512 + e] : 0.f;
    encT2[e*27 + p2] = packh2(e0, e1);
  }
  fwL[tid] = p.faw[tid];
  // (b) wA2: k2-slice = blk; vcols: 0-511 daw, 512-1023 fbw, 1024-2023 fcw
  {
    int k2 = blk, k = 2*k2;
    for (int vc = tid; vc < 2048; vc += NTHR){
      float w0 = 0.f, w1 = 0.f;
      if (vc < 512){ const float* r = p.daw + (size_t)vc*512 + k; w0 = r[0]; w1 = r[1]; }
      else if (vc < 1024){ const float* r = p.fbw + (size_t)(vc-512)*512 + k; w0 = r[0]; w1 = r[1]; }
      else if (vc < 2024){ const float* r = p.fcw + (size_t)(vc-1024)*512 + k; w0 = r[0]; w1 = r[1]; }
      p.wA2[((size_t)(k2>>1)*2048 + vc)*2 + (k2&1)] = packh2(w0, w1);
    }
  }
  // (c) wG2: k2-slices blk*3..+2; col c = j*4+g -> row g*512+j
  for (int s = 0; s < 3; s++){
    int k2 = blk*3 + s, k = 2*k2;
    for (int c = tid; c < 2048; c += NTHR){
      int j = c >> 2, g = c & 3, r = g*512 + j;
      float w0, w1;
      if (k2 < 512){ const float* rr = p.wih + (size_t)r*1024 + k; w0 = rr[0]; w1 = rr[1]; }
      else         { const float* rr = p.whh + (size_t)r*512 + (k-1024); w0 = rr[0]; w1 = rr[1]; }
      p.wG2[((size_t)(k2>>1)*2048 + c)*2 + (k2&1)] = packh2(w0, w1);
    }
  }
  // (d) h0/c0 for P3 slice (ct: 16 j's, bt: 8 b's)
  if (tid < 128){
    int jj = tid >> 3, bb2 = tid & 7;
    int b8 = bt*8 + bb2, jg = ct*16 + jj;
    const float* mrow = p.mnT + b8*512;
    const float* hw = p.ihw + (size_t)jg*512;
    const float* cw = p.icw + (size_t)jg*512;
    float ah = 0.f, ac = 0.f;
    for (int k = 0; k < 512; k++){ ah = fmaf(hw[k], mrow[k], ah); ac = fmaf(cw[k], mrow[k], ac); }
    stg_c(&p.hA[b8*512 + jg], ah + p.ihb[jg]);
    cL[jj*8 + bb2] = ac + p.icb[jg];
  }
  gridbar(p.bar, blk);

  const float fab0 = p.fab[0];
  int ep = 0;

  // ---------------- time loop: 3 fence-free grid bars + 1 group sync ----------------
  for (int t = 0; t < T_; t++){
    const float* hR = (t & 1) ? p.hB : p.hA;   // h(t)
    float*       hW = (t & 1) ? p.hA : p.hB;   // h(t+1)

    // ======== P1: a2+gate (ct<16) | preds(t-1) (ct>=16), by (64 vcols x 8 b) ========
    if (ct < 16){
      for (int i = tid; i < 2048; i += NTHR){
        int bb2 = i >> 8, k2 = i & 255;
        float2 v = ldg2_c(&hR[(bt*8 + bb2)*512 + 2*k2]);
        hL2[i] = packh2(v.x, v.y);
      }
      __syncthreads();
      const int bb = wave, b8 = bt*8 + bb;
      const int vc = ct*64 + lane;
      const uint2* wa = (const uint2*)p.wA2;
      const uint2* hx = ((const uint2*)hL2) + bb*128;
      float acc = 0.f;
      #pragma unroll 4
      for (int k4 = 0; k4 < 128; k4++){
        uint2 w = wa[k4*2048 + vc];
        uint2 x = hx[k4];
        acc = fdot2f(ash2(w.x), ash2(x.x), acc);
        acc = fdot2f(ash2(w.y), ash2(x.y), acc);
      }
      if (vc < 512) stg_c(&p.a2G[b8*512 + vc], acc + p.dab[vc]);
      else          stg_c(&p.gateG[b8*512 + (vc-512)], sigf(acc + p.fbb[vc-512]));
    } else if (t > 0){
      for (int i = tid; i < 2048; i += NTHR){
        int bb2 = i >> 8, k2 = i & 255;
        float2 v = ldg2_c(&p.hnG[(bt*8 + bb2)*512 + 2*k2]);
        hnL2[i] = packh2(v.x, v.y);
      }
      __syncthreads();
      const int bb = wave, b8 = bt*8 + bb;
      const int v = (ct-16)*64 + lane;
      if (v < 1000){
        const uint2* wa = (const uint2*)p.wA2;
        const uint2* hx = ((const uint2*)hnL2) + bb*128;
        float acc = 0.f;
        #pragma unroll 4
        for (int k4 = 0; k4 < 128; k4++){
          uint2 w = wa[k4*2048 + (1024 + v)];
          uint2 x = hx[k4];
          acc = fdot2f(ash2(w.x), ash2(x.x), acc);
          acc = fdot2f(ash2(w.y), ash2(x.y), acc);
        }
        bool mm = (t-1) < p.dec_len[b8];
        p.out[OUT_PRED + ((size_t)b8*T_ + (t-1))*V_ + v] = mm ? (acc + p.fcb[v]) : 0.f;
      }
    }
    treebar(p.tb, blk, ++ep);   // B1

    // ======== P2: attention (group of 4 blocks per b) ========
    {
      a2L[tid]   = ldg_c(&p.a2G[b*512 + tid]);
      gateL[tid] = ldg_c(&p.gateG[b*512 + tid]);
      if (tid < 128) stg_c(&p.xG[b*1024 + 512 + q*128 + tid], 0.f);
      {
        int cap = p.caps[sb*L_ + t];
        if (tid < 128)
          stg_c(&p.xG[b*1024 + q*128 + tid], p.emb[(size_t)cap*M_ + q*128 + tid]);
      }
      __syncthreads();
      // e for own 49 rows from bf16 att1L
      {
        float4 aA = ((float4*)a2L)[lane*2], aB = ((float4*)a2L)[lane*2+1];
        float4 fA = ((float4*)fwL)[lane*2], fB = ((float4*)fwL)[lane*2+1];
        for (int pp = wave; pp < 49; pp += 8){
          uint4 raw = ((const uint4*)att1L)[pp*64 + lane];
          float s =
            fmaxf(__uint_as_float(raw.x << 16)        + aA.x, 0.f)*fA.x +
            fmaxf(__uint_as_float(raw.x & 0xffff0000u)+ aA.y, 0.f)*fA.y +
            fmaxf(__uint_as_float(raw.y << 16)        + aA.z, 0.f)*fA.z +
            fmaxf(__uint_as_float(raw.y & 0xffff0000u)+ aA.w, 0.f)*fA.w +
            fmaxf(__uint_as_float(raw.z << 16)        + aB.x, 0.f)*fB.x +
            fmaxf(__uint_as_float(raw.z & 0xffff0000u)+ aB.y, 0.f)*fB.y +
            fmaxf(__uint_as_float(raw.w << 16)        + aB.z, 0.f)*fB.z +
            fmaxf(__uint_as_float(raw.w & 0xffff0000u)+ aB.w, 0.f)*fB.w;
          #pragma unroll
          for (int o = 32; o > 0; o >>= 1) s += __shfl_down(s, o);
          if (lane == 0) stg_c(&p.eG[b*256 + q*49 + pp], s + fab0);
        }
      }
      // group sync: e complete (also orders xG zero vs atomicAdd below)
      __syncthreads();
      if (tid == 0){
        FAA(&p.sy[b*16]);
        while (LD_A(&p.sy[b*16]) < 4*(t+1)) __builtin_amdgcn_s_sleep(1);
        asm volatile("" ::: "memory");
      }
      __syncthreads();
      if (tid < 196) eL[tid] = ldg_c(&p.eG[b*256 + tid]);
      __syncthreads();
      if (wave == 0){
        float mx = -1e30f;
        for (int i = lane; i < P_; i += 64) mx = fmaxf(mx, eL[i]);
        #pragma unroll
        for (int o = 32; o > 0; o >>= 1) mx = fmaxf(mx, __shfl_xor(mx, o));
        float sum = 0.f;
        for (int i = lane; i < P_; i += 64){
          float ex = __expf(eL[i] - mx);
          alphaL[i] = ex;
          sum += ex;
        }
        #pragma unroll
        for (int o = 32; o > 0; o >>= 1) sum += __shfl_xor(sum, o);
        float inv = 1.f / sum;
        for (int i = lane; i < P_; i += 64) alphaL[i] *= inv;
      }
      __syncthreads();
      {
        bool mb = t < dlb;
        if (tid < 49)
          p.out[OUT_ALPHA + ((size_t)b*T_ + t)*P_ + q*49 + tid] = mb ? alphaL[q*49 + tid] : 0.f;
        if (tid < 25){
          float a0 = alphaL[q*49 + 2*tid];
          float a1 = (2*tid+1 < 49) ? alphaL[q*49 + 2*tid + 1] : 0.f;
          alpha2L[tid] = packh2(a0, a1);
        }
      }
      __syncthreads();
      {
        const unsigned* ec = encT2 + tid*27;
        float s = 0.f;
        #pragma unroll 5
        for (int p2 = 0; p2 < 25; p2++)
          s = fdot2f(ash2(ec[p2]), ash2(alpha2L[p2]), s);
        __hip_atomic_fetch_add(&p.xG[b*1024 + 512 + tid], gateL[tid]*s,
                               __ATOMIC_RELAXED, __HIP_MEMORY_SCOPE_AGENT);
      }
    }
    treebar(p.tb, blk, ++ep);   // B2

    // ======== P3: gates GEMM (64 cols x 8 b, full K=1536) + LSTM ========
    {
      for (int bb2 = 0; bb2 < 8; bb2++){
        int b8 = bt*8 + bb2;
        for (int k2 = tid; k2 < 768; k2 += NTHR){
          int k = 2*k2;
          float2 v = (k < 1024) ? ldg2_c(&p.xG[b8*1024 + k])
                                : ldg2_c(&hR[b8*512 + (k-1024)]);
          xL2[bb2*768 + k2] = packh2(v.x, v.y);
        }
      }
      __syncthreads();
      const int bb = wave, c = ct*64 + lane;
      const uint2* wg = (const uint2*)p.wG2;
      const uint2* xx = ((const uint2*)xL2) + bb*384;
      float acc = 0.f;
      #pragma unroll 4
      for (int k4 = 0; k4 < 384; k4++){
        uint2 w = wg[k4*2048 + c];
        uint2 x = xx[k4];
        acc = fdot2f(ash2(w.x), ash2(x.x), acc);
        acc = fdot2f(ash2(w.y), ash2(x.y), acc);
      }
      red[lane*8 + bb] = acc;
      __syncthreads();
      if (tid < 128){
        int jj = tid >> 3, bb2 = tid & 7;
        int b8 = bt*8 + bb2, jg = ct*16 + jj;
        float g0 = red[(jj*4+0)*8 + bb2] + p.bih[jg]        + p.bhh[jg];
        float g1 = red[(jj*4+1)*8 + bb2] + p.bih[512 + jg]  + p.bhh[512 + jg];
        float g2 = red[(jj*4+2)*8 + bb2] + p.bih[1024 + jg] + p.bhh[1024 + jg];
        float g3 = red[(jj*4+3)*8 + bb2] + p.bih[1536 + jg] + p.bhh[1536 + jg];
        float i_s = sigf(g0), f_s = sigf(g1), g_t = tanhf_(g2), o_s = sigf(g3);
        float c_old = cL[jj*8 + bb2];
        float c_new = f_s*c_old + i_s*g_t;
        float h_new = o_s*tanhf_(c_new);
        bool m = t < p.dec_len[b8];
        float h_old = ldg_c(&hR[b8*512 + jg]);
        cL[jj*8 + bb2] = m ? c_new : c_old;
        stg_c(&p.hnG[b8*512 + jg], h_new);
        stg_c(&hW[b8*512 + jg], m ? h_new : h_old);
      }
    }
    treebar(p.tb, blk, ++ep);   // B0 (h(t+1), hn(t) published)
  }

  // ---- final preds for t = T-1 ----
  {
    for (int i = tid; i < 2048; i += NTHR){
      int bb2 = i >> 8, k2 = i & 255;
      float2 v = ldg2_c(&p.hnG[(bt*8 + bb2)*512 + 2*k2]);
      hnL2[i] = packh2(v.x, v.y);
    }
    __syncthreads();
    if (ct >= 16){
      const int bb = wave, b8 = bt*8 + bb;
      const int v = (ct-16)*64 + lane;
      if (v < 1000){
        const uint2* wa = (const uint2*)p.wA2;
        const uint2* hx = ((const uint2*)hnL2) + bb*128;
        float acc = 0.f;
        #pragma unroll 4
        for (int k4 = 0; k4 < 128; k4++){
          uint2 w = wa[k4*2048 + (1024 + v)];
          uint2 x = hx[k4];
          acc = fdot2f(ash2(w.x), ash2(x.x), acc);
          acc = fdot2f(ash2(w.y), ash2(x.y), acc);
        }
        bool mm = (T_-1) < p.dec_len[b8];
        p.out[OUT_PRED + ((size_t)b8*T_ + (T_-1))*V_ + v] = mm ? (acc + p.fcb[v]) : 0.f;
      }
    }
  }
}

extern "C" void kernel_launch(void* const* d_in, const int* in_sizes, int n_in,
                              void* d_out, int out_size, void* d_ws, size_t ws_size,
                              hipStream_t stream){
  (void)in_sizes; (void)n_in; (void)out_size; (void)ws_size;
  KP p;
  p.enc  = (const float*)d_in[0];
  p.caps = (const int*)  d_in[1];
  p.clen = (const int*)  d_in[2];
  p.emb  = (const float*)d_in[3];
  p.eaw  = (const float*)d_in[4];  p.eab = (const float*)d_in[5];
  p.daw  = (const float*)d_in[6];  p.dab = (const float*)d_in[7];
  p.faw  = (const float*)d_in[8];  p.fab = (const float*)d_in[9];
  p.wih  = (const float*)d_in[10]; p.bih = (const float*)d_in[11];
  p.whh  = (const float*)d_in[12]; p.bhh = (const float*)d_in[13];
  p.ihw  = (const float*)d_in[14]; p.ihb = (const float*)d_in[15];
  p.icw  = (const float*)d_in[16]; p.icb = (const float*)d_in[17];
  p.fbw  = (const float*)d_in[18]; p.fbb = (const float*)d_in[19];
  p.fcw  = (const float*)d_in[20]; p.fcb = (const float*)d_in[21];
  p.out  = (float*)d_out;

  char* ws = (char*)d_ws;
  size_t off = 0;
  p.bar = (int*)(ws + off); off += 1024;    // fenced pre-barrier
  p.tb  = (int*)(ws + off); off += 1024;    // monotonic loop barrier
  p.sy  = (int*)(ws + off); off += 64*16*4; // per-b group counters
  size_t zero_bytes = off;
  p.sort_ind = (int*)(ws + off); off += 64*4;
  p.dec_len  = (int*)(ws + off); off += 64*4;
  off = (off + 255) & ~(size_t)255;
  p.mnT   = (float*)(ws + off); off += (size_t)B_*512*4;
  p.hA    = (float*)(ws + off); off += (size_t)B_*512*4;
  p.hB    = (float*)(ws + off); off += (size_t)B_*512*4;
  p.hnG   = (float*)(ws + off); off += (size_t)B_*512*4;
  p.a2G   = (float*)(ws + off); off += (size_t)B_*512*4;
  p.gateG = (float*)(ws + off); off += (size_t)B_*512*4;
  p.xG    = (float*)(ws + off); off += (size_t)B_*1024*4;
  p.eG    = (float*)(ws + off); off += (size_t)B_*256*4;
  p.att1  = (float*)(ws + off); off += (size_t)B_*P_*A_*4;
  p.wA2   = (unsigned*)(ws + off); off += (size_t)256*2048*4;
  p.wG2   = (unsigned*)(ws + off); off += (size_t)768*2048*4;

  hipMemsetAsync(ws, 0, zero_bytes, stream);

  void* args[] = { (void*)&p };
  hipLaunchCooperativeKernel((const void*)dec_kernel,
                             dim3(NBLK), dim3(NTHR), args, 0, stream);
}